// Round 2
// baseline (606.585 us; speedup 1.0000x reference)
//
#include <hip/hip_runtime.h>
#include <math.h>

#define DIMN 2048
#define HDIM 256
#define NSIG 6
#define NHEADS 4
#define HEADDIM 64
#define SWHID 4096
#define BB 4
#define SSEQ 2048
#define EPSF 1e-6f
#define NBLK 512

__device__ __forceinline__ float wsum(float v) {
    #pragma unroll
    for (int m = 1; m < 64; m <<= 1) v += __shfl_xor(v, m, 64);
    return v;
}

__device__ __forceinline__ float dot4(float4 a, float4 b) {
    return a.x*b.x + a.y*b.y + a.z*b.z + a.w*b.w;
}

// Hand-rolled grid barrier (replaces cg::grid().sync(), which failed under
// the harness's graph capture in R0). Device-scope release-add + acquire
// spin: release forces XCD-L2 writeback of this block's prior stores
// (__syncthreads first drains every thread's vmcnt), acquire invalidates
// stale lines before any post-barrier read. Counters zeroed by kinit.
__device__ __forceinline__ void gsync(unsigned* bar) {
    __syncthreads();
    if (threadIdx.x == 0) {
        __hip_atomic_fetch_add(bar, 1u, __ATOMIC_RELEASE,
                               __HIP_MEMORY_SCOPE_AGENT);
        while (__hip_atomic_load(bar, __ATOMIC_ACQUIRE,
                                 __HIP_MEMORY_SCOPE_AGENT) < NBLK) {
            __builtin_amdgcn_s_sleep(2);
        }
    }
    __syncthreads();
}

struct Params {
    const float *ipw, *ipb, *spw, *spb;
    const float *epi, *ale, *ood, *cunc, *ece, *moral;
    const float *chw1, *chb1, *chw2, *chb2;
    const float *outw, *outb;
    const float *sumw1, *sumb1, *rms1;
    const float *sww1, *sww3, *sww2;
    const float *sumw2, *sumb2, *rms2;
    float *A, *C, *g, *us, *t1n, *h, *t2, *t3n, *accum;
    float *conf, *sig;
    unsigned *bar;
};

// Zero the barrier counters and accum each launch (workspace is re-poisoned
// between harness iterations). Stream order guarantees it precedes kchain.
__global__ __launch_bounds__(256) void kinit(float* accum, unsigned* bar) {
    int t = threadIdx.x;
    if (t < 8) accum[t] = 0.f;
    bar[t] = 0u;
}

// Prefetch one 8 KiB chunk of the SwiGLU weights into L2/L3 during otherwise
// idle latency-bound phases. c in [0, 8192): first 4096 chunks cover sw_w1,
// rest cover sw_w3. asm keep so the loads can't be DCE'd.
__device__ __forceinline__ void pf8k(const float* sww1, const float* sww3,
                                     int c, int lane) {
    if (c >= 8192) return;
    const float* base = (c < 4096) ? (sww1 + (size_t)c * 2048)
                                   : (sww3 + (size_t)(c - 4096) * 2048);
    const float4* p4 = (const float4*)base;
    float s = 0.f;
    #pragma unroll
    for (int k = 0; k < 8; k++) {
        float4 v = p4[k * 64 + lane];
        s += v.x + v.y + v.z + v.w;
    }
    asm volatile("" :: "v"(s));
}

// One kernel replaces k0, kUV, kB_front, k2, k3, k4, k5.
// 512 blocks x 256 threads, 64 KiB static LDS + __launch_bounds__(256,2)
// (VGPR<=256) -> exactly 2 blocks/CU, 512 co-resident blocks guaranteed,
// so the hand-rolled barrier cannot deadlock.
__global__ __launch_bounds__(256, 2) void kchain(Params p)
{
    __shared__ __align__(16) float smem[16384];   // 64 KiB, reused per phase
    int t = threadIdx.x, wv = t >> 6, lane = t & 63;
    int gw = blockIdx.x * 4 + wv;                 // global wave id 0..2047

    // ---- S0: A[r] = ipw[r,:].spw ; C[r] = ipw[r,:].spb + ipb[r] (768 rows).
    //          Idle waves prefetch sw_w1.
    if (gw < 768) {
        int r = gw;
        float4 w  = ((const float4*)(p.ipw + (size_t)r * HDIM))[lane];
        float4 a4 = ((const float4*)p.spw)[lane];
        float4 b4 = ((const float4*)p.spb)[lane];
        float aa = wsum(dot4(w, a4));
        float cc = wsum(dot4(w, b4));
        if (lane == 0) { p.A[r] = aa; p.C[r] = cc + p.ipb[r]; }
    } else {
        pf8k(p.sww1, p.sww3, gw - 768, lane);
    }
    gsync(p.bar + 0 * 32);

    // ---- S1: front-end on block 0 (signals, Gram attention, confidence,
    //          softmax, aBar, and g[b][m] which folds attention+out_w weights).
    //          All other blocks prefetch more sw_w1/sw_w3.
    if (blockIdx.x == 0) {
        float* sA   = smem;          // 768
        float* sC   = smem + 768;    // 768
        float* sSig = smem + 1536;   // 24  [b*6+k]
        float* sGram= smem + 1568;   // 16  [h*4+i]
        float* sAtt = smem + 1600;   // 576 [((b*4+h)*6+qi)*6+ki]
        float* sBar = smem + 2176;   // 96  [(b*4+h)*6+ki]
        float* sRedW= smem + 2272;   // 16  [b*4+wv]
        float* sHu  = smem + 2288;   // 16  [b*4+h]
        float* sHv  = smem + 2304;   // 16  [b*4+h]

        for (int r = t; r < 768; r += 256) { sA[r] = p.A[r]; sC[r] = p.C[r]; }

        {   // signals: wave wv handles batch b = wv
            int b = wv;
            float se = wsum(p.epi[b * 64 + lane]) * (1.f / 64.f);
            float sa = wsum(p.ale[b * 64 + lane]) * (1.f / 64.f);
            if (lane == 0) {
                sSig[b*6+0] = se; sSig[b*6+1] = sa;
                sSig[b*6+2] = p.ood[b]; sSig[b*6+3] = p.cunc[b];
                sSig[b*6+4] = p.ece[0]; sSig[b*6+5] = p.moral[b];
                #pragma unroll
                for (int k = 0; k < NSIG; k++) p.sig[b*6+k] = sSig[b*6+k];
            }
        }
        __syncthreads();

        {   // per-head Gram scalars: wave wv = head
            int h = wv;
            float aq = sA[h*64+lane],       cq = sC[h*64+lane];
            float ak = sA[256+h*64+lane],   ck = sC[256+h*64+lane];
            float g0 = wsum(aq*ak), g1 = wsum(aq*ck);
            float g2 = wsum(cq*ak), g3 = wsum(cq*ck);
            if (lane == 0) { sGram[h*4+0]=g0; sGram[h*4+1]=g1;
                             sGram[h*4+2]=g2; sGram[h*4+3]=g3; }
        }

        {   // confidence head: Linear(6,256) -> exact GELU -> Linear(256,1)
            float c1[NSIG];
            #pragma unroll
            for (int j = 0; j < NSIG; j++) c1[j] = p.chw1[t*NSIG+j];
            float cb = p.chb1[t], cw2 = p.chw2[t];
            #pragma unroll
            for (int b = 0; b < BB; b++) {
                float z = cb;
                #pragma unroll
                for (int j = 0; j < NSIG; j++) z += sSig[b*6+j] * c1[j];
                float gg = 0.5f * z * (1.f + erff(z * 0.70710678118654752f));
                float v = wsum(gg * cw2);
                if (lane == 0) sRedW[b*4+wv] = v;
            }
        }
        __syncthreads();
        if (t < BB) {
            float s = sRedW[t*4+0]+sRedW[t*4+1]+sRedW[t*4+2]+sRedW[t*4+3]
                    + p.chb2[0];
            p.conf[t] = 1.f / (1.f + expf(-s));
        }

        // scores + softmax: one (b,h,qi) per thread
        if (t < 96) {
            int b = t / 24, r = t % 24, h = r / 6, qi = r % 6;
            float sq = sSig[b*6+qi];
            float g0=sGram[h*4+0], g1=sGram[h*4+1];
            float g2=sGram[h*4+2], g3=sGram[h*4+3];
            float sc[NSIG]; float mx = -1e30f;
            #pragma unroll
            for (int ki = 0; ki < NSIG; ki++) {
                float sk = sSig[b*6+ki];
                float s = (g0*sq*sk + g1*sq + g2*sk + g3) * 0.125f;
                sc[ki] = s; mx = fmaxf(mx, s);
            }
            float den = 0;
            #pragma unroll
            for (int ki = 0; ki < NSIG; ki++) { sc[ki] = expf(sc[ki]-mx); den += sc[ki]; }
            float inv = 1.f / den;
            #pragma unroll
            for (int ki = 0; ki < NSIG; ki++)
                sAtt[((b*4+h)*6+qi)*6+ki] = sc[ki] * inv;
        }
        __syncthreads();

        // aBar(b,h,ki) = column mean of att
        if (t < 96) {
            int b = t / 24, r = t % 24, h = r / 6, ki = r % 6;
            float s = 0;
            #pragma unroll
            for (int qi = 0; qi < NSIG; qi++) s += sAtt[((b*4+h)*6+qi)*6+ki];
            sBar[(b*4+h)*6+ki] = s * (1.f / 6.f);
        }
        __syncthreads();

        // hu/hv per (b,h)
        if (t < 16) {
            int b = t >> 2, h = t & 3;
            float hu = 0, hv = 0;
            #pragma unroll
            for (int ki = 0; ki < NSIG; ki++) {
                float a = sBar[(b*4+h)*6+ki];
                hu += a * sSig[b*6+ki]; hv += a;
            }
            sHu[b*4+h] = hu; sHv[b*4+h] = hv;
        }
        __syncthreads();

        // g[b][m] = hu[b][m>>6]*A[512+m] + hv[b][m>>6]*C[512+m]
        {
            int m = t, hh = m >> 6;
            #pragma unroll
            for (int b = 0; b < BB; b++)
                p.g[b*HDIM+m] = sHu[b*4+hh]*sA[512+m] + sHv[b*4+hh]*sC[512+m];
        }
    } else {
        pf8k(p.sww1, p.sww3, 1280 + (gw - 4), lane);
    }
    gsync(p.bar + 1 * 32);

    // ---- S2: us[b][n] = outb[n] + dot(outw[n,:], g[b,:]) (256 waves).
    //          Idle waves prefetch rest of sw_w1 + head of sw_w3.
    if (gw < HDIM) {
        int n = gw;
        float4 w = ((const float4*)(p.outw + (size_t)n * HDIM))[lane];
        float ob = p.outb[n];
        #pragma unroll
        for (int b = 0; b < BB; b++) {
            float4 g4 = ((const float4*)(p.g + b * HDIM))[lane];
            float acc = wsum(dot4(w, g4));
            if (lane == 0) p.us[b * HDIM + n] = acc + ob;
        }
    } else {
        pf8k(p.sww1, p.sww3, 3324 + (gw - 256), lane);
    }
    gsync(p.bar + 2 * 32);

    // ---- S3: t1n[b][d] = (us[b].sumw1[d,:] + b1[d]) * rms1[d]; accum[b]+=pre^2
    {
        float* sred = smem + 12288;
        if (t < BB) sred[t] = 0.f;
        __syncthreads();
        int d = gw;
        float4 w = ((const float4*)(p.sumw1 + (size_t)d * HDIM))[lane];
        float acc[BB];
        #pragma unroll
        for (int b = 0; b < BB; b++)
            acc[b] = dot4(w, ((const float4*)(p.us + b * HDIM))[lane]);
        #pragma unroll
        for (int b = 0; b < BB; b++) acc[b] = wsum(acc[b]);
        if (lane == 0) {
            #pragma unroll
            for (int b = 0; b < BB; b++) {
                float v = acc[b] + p.sumb1[d];
                atomicAdd(&sred[b], v * v);
                p.t1n[b * DIMN + d] = v * p.rms1[d];
            }
        }
        __syncthreads();
        if (t < BB) atomicAdd(&p.accum[t], sred[t]);
    }
    gsync(p.bar + 3 * 32);

    // ---- S4: SwiGLU. Each wave does 2 rows j (4096 rows / 2048 waves).
    {
        #pragma unroll
        for (int k = 0; k < 8; k++)
            ((float4*)smem)[k * 256 + t] = ((const float4*)p.t1n)[k * 256 + t];
        __syncthreads();
        float s1[BB];
        #pragma unroll
        for (int b = 0; b < BB; b++)
            s1[b] = rsqrtf(p.accum[b] * (1.f / DIMN) + EPSF);
        #pragma unroll
        for (int jj = 0; jj < 2; jj++) {
            int j = blockIdx.x * 8 + wv * 2 + jj;
            const float4* r1 = (const float4*)(p.sww1 + (size_t)j * DIMN);
            const float4* r3 = (const float4*)(p.sww3 + (size_t)j * DIMN);
            float a1[BB] = {0,0,0,0}, a3[BB] = {0,0,0,0};
            #pragma unroll
            for (int it = 0; it < 8; it++) {
                float4 w1 = r1[it * 64 + lane];
                float4 w3 = r3[it * 64 + lane];
                #pragma unroll
                for (int b = 0; b < BB; b++) {
                    float4 tv = ((const float4*)(smem + b * DIMN))[it * 64 + lane];
                    a1[b] += dot4(w1, tv);
                    a3[b] += dot4(w3, tv);
                }
            }
            #pragma unroll
            for (int b = 0; b < BB; b++) { a1[b] = wsum(a1[b]); a3[b] = wsum(a3[b]); }
            if (lane == 0) {
                #pragma unroll
                for (int b = 0; b < BB; b++) {
                    float a = a1[b] * s1[b];
                    float sil = a / (1.f + expf(-a));
                    p.h[b * SWHID + j] = sil * (a3[b] * s1[b]);
                }
            }
        }
    }
    gsync(p.bar + 4 * 32);

    // ---- S5: t2[b][d] = dot(h[b], sw_w2[d,:])
    {
        #pragma unroll
        for (int k = 0; k < 16; k++)
            ((float4*)smem)[k * 256 + t] = ((const float4*)p.h)[k * 256 + t];
        __syncthreads();
        int d = gw;
        const float4* wr = (const float4*)(p.sww2 + (size_t)d * SWHID);
        float acc[BB] = {0,0,0,0};
        #pragma unroll
        for (int it = 0; it < 16; it++) {
            float4 w = wr[it * 64 + lane];
            #pragma unroll
            for (int b = 0; b < BB; b++)
                acc[b] += dot4(w, ((const float4*)(smem + b * SWHID))[it * 64 + lane]);
        }
        #pragma unroll
        for (int b = 0; b < BB; b++) acc[b] = wsum(acc[b]);
        if (lane == 0) {
            #pragma unroll
            for (int b = 0; b < BB; b++) p.t2[b * DIMN + d] = acc[b];
        }
    }
    gsync(p.bar + 5 * 32);

    // ---- S6: t3n[b][d] = (t2[b].sumw2[d,:] + b2[d]) * rms2[d]; accum[4+b]+=pre^2
    {
        float* sred = smem + 12288;        // disjoint from 32 KiB t2 stage
        if (t < BB) sred[t] = 0.f;
        #pragma unroll
        for (int k = 0; k < 8; k++)
            ((float4*)smem)[k * 256 + t] = ((const float4*)p.t2)[k * 256 + t];
        __syncthreads();
        int d = gw;
        const float4* wr = (const float4*)(p.sumw2 + (size_t)d * DIMN);
        float acc[BB] = {0,0,0,0};
        #pragma unroll
        for (int it = 0; it < 8; it++) {
            float4 w = wr[it * 64 + lane];
            #pragma unroll
            for (int b = 0; b < BB; b++)
                acc[b] += dot4(w, ((const float4*)(smem + b * DIMN))[it * 64 + lane]);
        }
        #pragma unroll
        for (int b = 0; b < BB; b++) acc[b] = wsum(acc[b]);
        if (lane == 0) {
            #pragma unroll
            for (int b = 0; b < BB; b++) {
                float v = acc[b] + p.sumb2[d];
                atomicAdd(&sred[b], v * v);
                p.t3n[b * DIMN + d] = v * p.rms2[d];
            }
        }
        __syncthreads();
        if (t < BB) atomicAdd(&p.accum[4 + t], sred[t]);
    }
    // no final barrier: k7 is a separate launch (kernel boundary = fence)
}

// K7: unchanged from baseline (control variable).
__global__ __launch_bounds__(256) void k7_final(
    const float* __restrict__ x, const float* __restrict__ t3n,
    const float* __restrict__ accum, const float* __restrict__ nw,
    float* __restrict__ xa, float* __restrict__ ue)
{
    int t = threadIdx.x, wv = t >> 6, lane = t & 63;
    size_t row = (size_t)blockIdx.x * 4 + wv;
    int b = (int)(row >> 11);  // S = 2048
    float scale2 = rsqrtf(accum[4 + b] * (1.f / DIMN) + EPSF);
    const float4* xr = (const float4*)(x + row * DIMN);
    const float4* tr = (const float4*)(t3n + (size_t)b * DIMN);
    float4 e[8], y[8];
    float ss = 0.f;
    #pragma unroll
    for (int k = 0; k < 8; k++) {
        int idx = k * 64 + lane;
        float4 tv = tr[idx];
        float4 xv = xr[idx];
        e[k].x = tv.x * scale2; e[k].y = tv.y * scale2;
        e[k].z = tv.z * scale2; e[k].w = tv.w * scale2;
        y[k].x = xv.x + 0.05f * e[k].x; y[k].y = xv.y + 0.05f * e[k].y;
        y[k].z = xv.z + 0.05f * e[k].z; y[k].w = xv.w + 0.05f * e[k].w;
        ss += dot4(y[k], y[k]);
    }
    float rs = rsqrtf(wsum(ss) * (1.f / DIMN) + EPSF);
    float4* xo = (float4*)(xa + row * DIMN);
    float4* uo = (float4*)(ue + row * DIMN);
    #pragma unroll
    for (int k = 0; k < 8; k++) {
        int idx = k * 64 + lane;
        float4 nv = ((const float4*)nw)[idx];
        float4 o;
        o.x = y[k].x * rs * nv.x; o.y = y[k].y * rs * nv.y;
        o.z = y[k].z * rs * nv.z; o.w = y[k].w * rs * nv.w;
        xo[idx] = o;
        uo[idx] = e[k];
    }
}

extern "C" void kernel_launch(void* const* d_in, const int* in_sizes, int n_in,
                              void* d_out, int out_size, void* d_ws, size_t ws_size,
                              hipStream_t stream)
{
    (void)in_sizes; (void)n_in; (void)out_size; (void)ws_size;
    const float* x     = (const float*)d_in[0];

    float* out  = (float*)d_out;
    float* xa   = out;                                   // [4,2048,2048]
    float* conf = out + (size_t)BB * SSEQ * DIMN;        // [4]
    float* sig  = conf + BB;                             // [4,6]
    float* ue   = sig + BB * NSIG;                       // [4,2048,2048]

    float* ws = (float*)d_ws;

    Params hp;
    hp.ipw   = (const float*)d_in[9];
    hp.ipb   = (const float*)d_in[10];
    hp.spw   = (const float*)d_in[7];
    hp.spb   = (const float*)d_in[8];
    hp.epi   = (const float*)d_in[1];
    hp.ale   = (const float*)d_in[2];
    hp.ood   = (const float*)d_in[3];
    hp.cunc  = (const float*)d_in[4];
    hp.ece   = (const float*)d_in[5];
    hp.moral = (const float*)d_in[6];
    hp.chw1  = (const float*)d_in[13];
    hp.chb1  = (const float*)d_in[14];
    hp.chw2  = (const float*)d_in[15];
    hp.chb2  = (const float*)d_in[16];
    hp.outw  = (const float*)d_in[11];
    hp.outb  = (const float*)d_in[12];
    hp.sumw1 = (const float*)d_in[17];
    hp.sumb1 = (const float*)d_in[18];
    hp.rms1  = (const float*)d_in[19];
    hp.sww1  = (const float*)d_in[20];
    hp.sww3  = (const float*)d_in[21];
    hp.sww2  = (const float*)d_in[22];
    hp.sumw2 = (const float*)d_in[23];
    hp.sumb2 = (const float*)d_in[24];
    hp.rms2  = (const float*)d_in[25];

    hp.A     = ws;              // 768
    hp.C     = ws + 768;        // 768
    hp.g     = ws + 1536;       // 1024
    hp.us    = ws + 2560;       // 1024
    hp.t1n   = ws + 3584;       // 8192
    hp.h     = ws + 11776;      // 16384
    hp.t2    = ws + 28160;      // 8192
    hp.t3n   = ws + 36352;      // 8192
    hp.accum = ws + 44544;      // 8
    hp.bar   = (unsigned*)(ws + 44800); // 256 uints (8 counters, 128B apart)
    hp.conf  = conf;
    hp.sig   = sig;

    kinit<<<1, 256, 0, stream>>>(hp.accum, hp.bar);
    kchain<<<NBLK, 256, 0, stream>>>(hp);
    k7_final<<<2048, 256, 0, stream>>>(x, hp.t3n, hp.accum,
                                       (const float*)d_in[26], xa, ue);
}

// Round 3
// 469.601 us; speedup vs baseline: 1.2917x; 1.2917x over previous
//
#include <hip/hip_runtime.h>
#include <math.h>

#define DIMN 2048
#define HDIM 256
#define NSIG 6
#define NHEADS 4
#define HEADDIM 64
#define SWHID 4096
#define BB 4
#define SSEQ 2048
#define EPSF 1e-6f
#define NBLK 512

// Barrier layout: per barrier, 64 group-counter lines + 1 root line + 1 flag
// line (32 uints = 128 B each).
#define NBAR 6
#define BARSTRIDE (66 * 32)

__device__ __forceinline__ float wsum(float v) {
    #pragma unroll
    for (int m = 1; m < 64; m <<= 1) v += __shfl_xor(v, m, 64);
    return v;
}

__device__ __forceinline__ float dot4(float4 a, float4 b) {
    return a.x*b.x + a.y*b.y + a.z*b.z + a.w*b.w;
}

// Two-level tree barrier + broadcast flag.
// R2's flat barrier (512 same-line RMWs + ACQUIRE-spin) stalled the kernel
// ~95%: acquire-per-spin-iteration = continuous L2 invalidate storm from 512
// spinners, wiping prefetched weights and in-phase streams. Here:
//  - arrivals: 8 RMWs on each of 64 parallel lines, 64 RMWs on one root line
//  - wait: RELAXED agent loads (coherence-point read, NO invalidate) + sleep
//  - one acquire load after exit = exactly one invalidate per block per phase
// Release-sequence chain gc(acq_rel) -> rc(acq_rel) -> flag(release) keeps
// all pre-barrier stores visible to all post-barrier reads.
__device__ __forceinline__ void gsync(unsigned* base) {
    __syncthreads();
    if (threadIdx.x == 0) {
        unsigned* gc = base + (blockIdx.x >> 3) * 32;  // 64 groups of 8
        unsigned* rc = base + 64 * 32;
        unsigned* fl = base + 65 * 32;
        if (__hip_atomic_fetch_add(gc, 1u, __ATOMIC_ACQ_REL,
                                   __HIP_MEMORY_SCOPE_AGENT) == 7u) {
            if (__hip_atomic_fetch_add(rc, 1u, __ATOMIC_ACQ_REL,
                                       __HIP_MEMORY_SCOPE_AGENT) == 63u) {
                __hip_atomic_store(fl, 1u, __ATOMIC_RELEASE,
                                   __HIP_MEMORY_SCOPE_AGENT);
            }
        }
        while (__hip_atomic_load(fl, __ATOMIC_RELAXED,
                                 __HIP_MEMORY_SCOPE_AGENT) == 0u) {
            __builtin_amdgcn_s_sleep(8);
        }
        (void)__hip_atomic_load(fl, __ATOMIC_ACQUIRE,
                                __HIP_MEMORY_SCOPE_AGENT);
    }
    __syncthreads();
}

struct Params {
    const float *ipw, *ipb, *spw, *spb;
    const float *epi, *ale, *ood, *cunc, *ece, *moral;
    const float *chw1, *chb1, *chw2, *chb2;
    const float *outw, *outb;
    const float *sumw1, *sumb1, *rms1;
    const float *sww1, *sww3, *sww2;
    const float *sumw2, *sumb2, *rms2;
    float *A, *C, *g, *us, *t1n, *h, *t2, *t3n, *accum;
    float *conf, *sig;
    unsigned *bar;
};

// Zero barrier counters + accum each launch (workspace re-poisoned between
// iterations). Stream order guarantees this precedes kchain.
__global__ __launch_bounds__(256) void kinit(float* accum, unsigned* bar) {
    int t = threadIdx.x;
    if (t < 8) accum[t] = 0.f;
    for (int i = t; i < NBAR * BARSTRIDE; i += 256) bar[i] = 0u;
}

// Prefetch one 8 KiB chunk of the SwiGLU weights into L2/L3 during otherwise
// idle latency-bound phases. c in [0, 8192): first 4096 chunks cover sw_w1,
// rest cover sw_w3. asm keep so the loads can't be DCE'd.
__device__ __forceinline__ void pf8k(const float* sww1, const float* sww3,
                                     int c, int lane) {
    if (c >= 8192) return;
    const float* base = (c < 4096) ? (sww1 + (size_t)c * 2048)
                                   : (sww3 + (size_t)(c - 4096) * 2048);
    const float4* p4 = (const float4*)base;
    float s = 0.f;
    #pragma unroll
    for (int k = 0; k < 8; k++) {
        float4 v = p4[k * 64 + lane];
        s += v.x + v.y + v.z + v.w;
    }
    asm volatile("" :: "v"(s));
}

// One kernel replaces k0, kUV, kB_front, k2, k3, k4, k5.
// 512 blocks x 256 threads, 64 KiB static LDS + __launch_bounds__(256,2)
// -> exactly 2 blocks/CU, all 512 blocks co-resident (proven in R2), so the
// hand-rolled barrier cannot deadlock.
__global__ __launch_bounds__(256, 2) void kchain(Params p)
{
    __shared__ __align__(16) float smem[16384];   // 64 KiB, reused per phase
    int t = threadIdx.x, wv = t >> 6, lane = t & 63;
    int gw = blockIdx.x * 4 + wv;                 // global wave id 0..2047

    // ---- S0: A[r] = ipw[r,:].spw ; C[r] = ipw[r,:].spb + ipb[r] (768 rows).
    //          Idle waves prefetch sw_w1.
    if (gw < 768) {
        int r = gw;
        float4 w  = ((const float4*)(p.ipw + (size_t)r * HDIM))[lane];
        float4 a4 = ((const float4*)p.spw)[lane];
        float4 b4 = ((const float4*)p.spb)[lane];
        float aa = wsum(dot4(w, a4));
        float cc = wsum(dot4(w, b4));
        if (lane == 0) { p.A[r] = aa; p.C[r] = cc + p.ipb[r]; }
    } else {
        pf8k(p.sww1, p.sww3, gw - 768, lane);
    }
    gsync(p.bar + 0 * BARSTRIDE);

    // ---- S1: front-end on block 0 (signals, Gram attention, confidence,
    //          softmax, aBar, and g[b][m] which folds attention+out_w weights).
    //          All other blocks prefetch more sw_w1/sw_w3.
    if (blockIdx.x == 0) {
        float* sA   = smem;          // 768
        float* sC   = smem + 768;    // 768
        float* sSig = smem + 1536;   // 24  [b*6+k]
        float* sGram= smem + 1568;   // 16  [h*4+i]
        float* sAtt = smem + 1600;   // 576 [((b*4+h)*6+qi)*6+ki]
        float* sBar = smem + 2176;   // 96  [(b*4+h)*6+ki]
        float* sRedW= smem + 2272;   // 16  [b*4+wv]
        float* sHu  = smem + 2288;   // 16  [b*4+h]
        float* sHv  = smem + 2304;   // 16  [b*4+h]

        for (int r = t; r < 768; r += 256) { sA[r] = p.A[r]; sC[r] = p.C[r]; }

        {   // signals: wave wv handles batch b = wv
            int b = wv;
            float se = wsum(p.epi[b * 64 + lane]) * (1.f / 64.f);
            float sa = wsum(p.ale[b * 64 + lane]) * (1.f / 64.f);
            if (lane == 0) {
                sSig[b*6+0] = se; sSig[b*6+1] = sa;
                sSig[b*6+2] = p.ood[b]; sSig[b*6+3] = p.cunc[b];
                sSig[b*6+4] = p.ece[0]; sSig[b*6+5] = p.moral[b];
                #pragma unroll
                for (int k = 0; k < NSIG; k++) p.sig[b*6+k] = sSig[b*6+k];
            }
        }
        __syncthreads();

        {   // per-head Gram scalars: wave wv = head
            int h = wv;
            float aq = sA[h*64+lane],       cq = sC[h*64+lane];
            float ak = sA[256+h*64+lane],   ck = sC[256+h*64+lane];
            float g0 = wsum(aq*ak), g1 = wsum(aq*ck);
            float g2 = wsum(cq*ak), g3 = wsum(cq*ck);
            if (lane == 0) { sGram[h*4+0]=g0; sGram[h*4+1]=g1;
                             sGram[h*4+2]=g2; sGram[h*4+3]=g3; }
        }

        {   // confidence head: Linear(6,256) -> exact GELU -> Linear(256,1)
            float c1[NSIG];
            #pragma unroll
            for (int j = 0; j < NSIG; j++) c1[j] = p.chw1[t*NSIG+j];
            float cb = p.chb1[t], cw2 = p.chw2[t];
            #pragma unroll
            for (int b = 0; b < BB; b++) {
                float z = cb;
                #pragma unroll
                for (int j = 0; j < NSIG; j++) z += sSig[b*6+j] * c1[j];
                float gg = 0.5f * z * (1.f + erff(z * 0.70710678118654752f));
                float v = wsum(gg * cw2);
                if (lane == 0) sRedW[b*4+wv] = v;
            }
        }
        __syncthreads();
        if (t < BB) {
            float s = sRedW[t*4+0]+sRedW[t*4+1]+sRedW[t*4+2]+sRedW[t*4+3]
                    + p.chb2[0];
            p.conf[t] = 1.f / (1.f + expf(-s));
        }

        // scores + softmax: one (b,h,qi) per thread
        if (t < 96) {
            int b = t / 24, r = t % 24, h = r / 6, qi = r % 6;
            float sq = sSig[b*6+qi];
            float g0=sGram[h*4+0], g1=sGram[h*4+1];
            float g2=sGram[h*4+2], g3=sGram[h*4+3];
            float sc[NSIG]; float mx = -1e30f;
            #pragma unroll
            for (int ki = 0; ki < NSIG; ki++) {
                float sk = sSig[b*6+ki];
                float s = (g0*sq*sk + g1*sq + g2*sk + g3) * 0.125f;
                sc[ki] = s; mx = fmaxf(mx, s);
            }
            float den = 0;
            #pragma unroll
            for (int ki = 0; ki < NSIG; ki++) { sc[ki] = expf(sc[ki]-mx); den += sc[ki]; }
            float inv = 1.f / den;
            #pragma unroll
            for (int ki = 0; ki < NSIG; ki++)
                sAtt[((b*4+h)*6+qi)*6+ki] = sc[ki] * inv;
        }
        __syncthreads();

        // aBar(b,h,ki) = column mean of att
        if (t < 96) {
            int b = t / 24, r = t % 24, h = r / 6, ki = r % 6;
            float s = 0;
            #pragma unroll
            for (int qi = 0; qi < NSIG; qi++) s += sAtt[((b*4+h)*6+qi)*6+ki];
            sBar[(b*4+h)*6+ki] = s * (1.f / 6.f);
        }
        __syncthreads();

        // hu/hv per (b,h)
        if (t < 16) {
            int b = t >> 2, h = t & 3;
            float hu = 0, hv = 0;
            #pragma unroll
            for (int ki = 0; ki < NSIG; ki++) {
                float a = sBar[(b*4+h)*6+ki];
                hu += a * sSig[b*6+ki]; hv += a;
            }
            sHu[b*4+h] = hu; sHv[b*4+h] = hv;
        }
        __syncthreads();

        // g[b][m] = hu[b][m>>6]*A[512+m] + hv[b][m>>6]*C[512+m]
        {
            int m = t, hh = m >> 6;
            #pragma unroll
            for (int b = 0; b < BB; b++)
                p.g[b*HDIM+m] = sHu[b*4+hh]*sA[512+m] + sHv[b*4+hh]*sC[512+m];
        }
    } else {
        pf8k(p.sww1, p.sww3, 1280 + (gw - 4), lane);
    }
    gsync(p.bar + 1 * BARSTRIDE);

    // ---- S2: us[b][n] = outb[n] + dot(outw[n,:], g[b,:]) (256 waves).
    //          Idle waves prefetch rest of sw_w1 + head of sw_w3.
    if (gw < HDIM) {
        int n = gw;
        float4 w = ((const float4*)(p.outw + (size_t)n * HDIM))[lane];
        float ob = p.outb[n];
        #pragma unroll
        for (int b = 0; b < BB; b++) {
            float4 g4 = ((const float4*)(p.g + b * HDIM))[lane];
            float acc = wsum(dot4(w, g4));
            if (lane == 0) p.us[b * HDIM + n] = acc + ob;
        }
    } else {
        pf8k(p.sww1, p.sww3, 3324 + (gw - 256), lane);
    }
    gsync(p.bar + 2 * BARSTRIDE);

    // ---- S3: t1n[b][d] = (us[b].sumw1[d,:] + b1[d]) * rms1[d]; accum[b]+=pre^2
    {
        float* sred = smem + 12288;
        if (t < BB) sred[t] = 0.f;
        __syncthreads();
        int d = gw;
        float4 w = ((const float4*)(p.sumw1 + (size_t)d * HDIM))[lane];
        float acc[BB];
        #pragma unroll
        for (int b = 0; b < BB; b++)
            acc[b] = dot4(w, ((const float4*)(p.us + b * HDIM))[lane]);
        #pragma unroll
        for (int b = 0; b < BB; b++) acc[b] = wsum(acc[b]);
        if (lane == 0) {
            #pragma unroll
            for (int b = 0; b < BB; b++) {
                float v = acc[b] + p.sumb1[d];
                atomicAdd(&sred[b], v * v);
                p.t1n[b * DIMN + d] = v * p.rms1[d];
            }
        }
        __syncthreads();
        if (t < BB) atomicAdd(&p.accum[t], sred[t]);
    }
    gsync(p.bar + 3 * BARSTRIDE);

    // ---- S4: SwiGLU. Each wave does 2 rows j (4096 rows / 2048 waves).
    {
        #pragma unroll
        for (int k = 0; k < 8; k++)
            ((float4*)smem)[k * 256 + t] = ((const float4*)p.t1n)[k * 256 + t];
        __syncthreads();
        float s1[BB];
        #pragma unroll
        for (int b = 0; b < BB; b++)
            s1[b] = rsqrtf(p.accum[b] * (1.f / DIMN) + EPSF);
        #pragma unroll
        for (int jj = 0; jj < 2; jj++) {
            int j = blockIdx.x * 8 + wv * 2 + jj;
            const float4* r1 = (const float4*)(p.sww1 + (size_t)j * DIMN);
            const float4* r3 = (const float4*)(p.sww3 + (size_t)j * DIMN);
            float a1[BB] = {0,0,0,0}, a3[BB] = {0,0,0,0};
            #pragma unroll
            for (int it = 0; it < 8; it++) {
                float4 w1 = r1[it * 64 + lane];
                float4 w3 = r3[it * 64 + lane];
                #pragma unroll
                for (int b = 0; b < BB; b++) {
                    float4 tv = ((const float4*)(smem + b * DIMN))[it * 64 + lane];
                    a1[b] += dot4(w1, tv);
                    a3[b] += dot4(w3, tv);
                }
            }
            #pragma unroll
            for (int b = 0; b < BB; b++) { a1[b] = wsum(a1[b]); a3[b] = wsum(a3[b]); }
            if (lane == 0) {
                #pragma unroll
                for (int b = 0; b < BB; b++) {
                    float a = a1[b] * s1[b];
                    float sil = a / (1.f + expf(-a));
                    p.h[b * SWHID + j] = sil * (a3[b] * s1[b]);
                }
            }
        }
    }
    gsync(p.bar + 4 * BARSTRIDE);

    // ---- S5: t2[b][d] = dot(h[b], sw_w2[d,:])
    {
        #pragma unroll
        for (int k = 0; k < 16; k++)
            ((float4*)smem)[k * 256 + t] = ((const float4*)p.h)[k * 256 + t];
        __syncthreads();
        int d = gw;
        const float4* wr = (const float4*)(p.sww2 + (size_t)d * SWHID);
        float acc[BB] = {0,0,0,0};
        #pragma unroll
        for (int it = 0; it < 16; it++) {
            float4 w = wr[it * 64 + lane];
            #pragma unroll
            for (int b = 0; b < BB; b++)
                acc[b] += dot4(w, ((const float4*)(smem + b * SWHID))[it * 64 + lane]);
        }
        #pragma unroll
        for (int b = 0; b < BB; b++) acc[b] = wsum(acc[b]);
        if (lane == 0) {
            #pragma unroll
            for (int b = 0; b < BB; b++) p.t2[b * DIMN + d] = acc[b];
        }
    }
    gsync(p.bar + 5 * BARSTRIDE);

    // ---- S6: t3n[b][d] = (t2[b].sumw2[d,:] + b2[d]) * rms2[d]; accum[4+b]+=pre^2
    {
        float* sred = smem + 12288;        // disjoint from 32 KiB t2 stage
        if (t < BB) sred[t] = 0.f;
        #pragma unroll
        for (int k = 0; k < 8; k++)
            ((float4*)smem)[k * 256 + t] = ((const float4*)p.t2)[k * 256 + t];
        __syncthreads();
        int d = gw;
        const float4* wr = (const float4*)(p.sumw2 + (size_t)d * DIMN);
        float acc[BB] = {0,0,0,0};
        #pragma unroll
        for (int it = 0; it < 8; it++) {
            float4 w = wr[it * 64 + lane];
            #pragma unroll
            for (int b = 0; b < BB; b++)
                acc[b] += dot4(w, ((const float4*)(smem + b * DIMN))[it * 64 + lane]);
        }
        #pragma unroll
        for (int b = 0; b < BB; b++) acc[b] = wsum(acc[b]);
        if (lane == 0) {
            #pragma unroll
            for (int b = 0; b < BB; b++) {
                float v = acc[b] + p.sumb2[d];
                atomicAdd(&sred[b], v * v);
                p.t3n[b * DIMN + d] = v * p.rms2[d];
            }
        }
        __syncthreads();
        if (t < BB) atomicAdd(&p.accum[4 + t], sred[t]);
    }
    // no final barrier: k7 is a separate launch (kernel boundary = fence)
}

// K7: unchanged from baseline (control variable).
__global__ __launch_bounds__(256) void k7_final(
    const float* __restrict__ x, const float* __restrict__ t3n,
    const float* __restrict__ accum, const float* __restrict__ nw,
    float* __restrict__ xa, float* __restrict__ ue)
{
    int t = threadIdx.x, wv = t >> 6, lane = t & 63;
    size_t row = (size_t)blockIdx.x * 4 + wv;
    int b = (int)(row >> 11);  // S = 2048
    float scale2 = rsqrtf(accum[4 + b] * (1.f / DIMN) + EPSF);
    const float4* xr = (const float4*)(x + row * DIMN);
    const float4* tr = (const float4*)(t3n + (size_t)b * DIMN);
    float4 e[8], y[8];
    float ss = 0.f;
    #pragma unroll
    for (int k = 0; k < 8; k++) {
        int idx = k * 64 + lane;
        float4 tv = tr[idx];
        float4 xv = xr[idx];
        e[k].x = tv.x * scale2; e[k].y = tv.y * scale2;
        e[k].z = tv.z * scale2; e[k].w = tv.w * scale2;
        y[k].x = xv.x + 0.05f * e[k].x; y[k].y = xv.y + 0.05f * e[k].y;
        y[k].z = xv.z + 0.05f * e[k].z; y[k].w = xv.w + 0.05f * e[k].w;
        ss += dot4(y[k], y[k]);
    }
    float rs = rsqrtf(wsum(ss) * (1.f / DIMN) + EPSF);
    float4* xo = (float4*)(xa + row * DIMN);
    float4* uo = (float4*)(ue + row * DIMN);
    #pragma unroll
    for (int k = 0; k < 8; k++) {
        int idx = k * 64 + lane;
        float4 nv = ((const float4*)nw)[idx];
        float4 o;
        o.x = y[k].x * rs * nv.x; o.y = y[k].y * rs * nv.y;
        o.z = y[k].z * rs * nv.z; o.w = y[k].w * rs * nv.w;
        xo[idx] = o;
        uo[idx] = e[k];
    }
}

extern "C" void kernel_launch(void* const* d_in, const int* in_sizes, int n_in,
                              void* d_out, int out_size, void* d_ws, size_t ws_size,
                              hipStream_t stream)
{
    (void)in_sizes; (void)n_in; (void)out_size; (void)ws_size;
    const float* x     = (const float*)d_in[0];

    float* out  = (float*)d_out;
    float* xa   = out;                                   // [4,2048,2048]
    float* conf = out + (size_t)BB * SSEQ * DIMN;        // [4]
    float* sig  = conf + BB;                             // [4,6]
    float* ue   = sig + BB * NSIG;                       // [4,2048,2048]

    float* ws = (float*)d_ws;

    Params hp;
    hp.ipw   = (const float*)d_in[9];
    hp.ipb   = (const float*)d_in[10];
    hp.spw   = (const float*)d_in[7];
    hp.spb   = (const float*)d_in[8];
    hp.epi   = (const float*)d_in[1];
    hp.ale   = (const float*)d_in[2];
    hp.ood   = (const float*)d_in[3];
    hp.cunc  = (const float*)d_in[4];
    hp.ece   = (const float*)d_in[5];
    hp.moral = (const float*)d_in[6];
    hp.chw1  = (const float*)d_in[13];
    hp.chb1  = (const float*)d_in[14];
    hp.chw2  = (const float*)d_in[15];
    hp.chb2  = (const float*)d_in[16];
    hp.outw  = (const float*)d_in[11];
    hp.outb  = (const float*)d_in[12];
    hp.sumw1 = (const float*)d_in[17];
    hp.sumb1 = (const float*)d_in[18];
    hp.rms1  = (const float*)d_in[19];
    hp.sww1  = (const float*)d_in[20];
    hp.sww3  = (const float*)d_in[21];
    hp.sww2  = (const float*)d_in[22];
    hp.sumw2 = (const float*)d_in[23];
    hp.sumb2 = (const float*)d_in[24];
    hp.rms2  = (const float*)d_in[25];

    hp.A     = ws;              // 768
    hp.C     = ws + 768;        // 768
    hp.g     = ws + 1536;       // 1024
    hp.us    = ws + 2560;       // 1024
    hp.t1n   = ws + 3584;       // 8192
    hp.h     = ws + 11776;      // 16384
    hp.t2    = ws + 28160;      // 8192
    hp.t3n   = ws + 36352;      // 8192
    hp.accum = ws + 44544;      // 8
    hp.bar   = (unsigned*)(ws + 44800); // NBAR*BARSTRIDE uints
    hp.conf  = conf;
    hp.sig   = sig;

    kinit<<<1, 256, 0, stream>>>(hp.accum, hp.bar);
    kchain<<<NBLK, 256, 0, stream>>>(hp);
    k7_final<<<2048, 256, 0, stream>>>(x, hp.t3n, hp.accum,
                                       (const float*)d_in[26], xa, ue);
}